// Round 18
// baseline (594.078 us; speedup 1.0000x reference)
//
#include <hip/hip_runtime.h>
#include <hip/hip_bf16.h>

#define N_TOK 4096
#define DIM   1024
#define HID   4096
#define NEXP  8
#define NPOS  8192

#define BK    32
#define BSTR  36                     // B LDS row stride in shorts (72B: 8B-aligned, odd dw)
#define MAXT1 40                     // BM=256 m-tiles max
#define MAXT2 72                     // BM=128 m-tiles max
#define G1    (MAXT1 * (HID/128))    // 1280 ffn1 blocks
#define G2    (MAXT2 * (DIM/128))    // 576 ffn2 blocks (full K, n0-fast order)

typedef float  f32x4  __attribute__((ext_vector_type(4)));
typedef float  f32x2  __attribute__((ext_vector_type(2)));
typedef __bf16 bf16x8 __attribute__((ext_vector_type(8)));
typedef unsigned short us8 __attribute__((ext_vector_type(8)));
typedef unsigned short us4 __attribute__((ext_vector_type(4)));

__device__ __forceinline__ unsigned short f2bf(float f) {
  __hip_bfloat16 h = __float2bfloat16(f);
  return *reinterpret_cast<unsigned short*>(&h);
}
__device__ __forceinline__ void gload16(const void* g, void* l) {
  __builtin_amdgcn_global_load_lds(
      (const __attribute__((address_space(1))) unsigned int*)g,
      (__attribute__((address_space(3))) unsigned int*)l, 16, 0, 0);
}
#define BAR()    __builtin_amdgcn_s_barrier()
#define WAITV0() asm volatile("s_waitcnt vmcnt(0)" ::: "memory")
#define WAITL()  asm volatile("s_waitcnt lgkmcnt(0)" ::: "memory")

// ============ K1: gate + x->bf16 (pure, no transpose work) ============
__global__ __launch_bounds__(256) void gate_kernel(
    const float* __restrict__ x, const float* __restrict__ Wg,
    const float* __restrict__ bg, int* __restrict__ topk_idx,
    float* __restrict__ topk_w, int* __restrict__ expert_count,
    unsigned short* __restrict__ xb)
{
  const int tid = threadIdx.x;
  const int wave = tid >> 6, lane = tid & 63;
  const int t = blockIdx.x * 4 + wave;
  const float* xr = x + (size_t)t * DIM;
  unsigned short* xbr = xb + (size_t)t * DIM;

  float acc[NEXP];
#pragma unroll
  for (int e = 0; e < NEXP; e++) acc[e] = 0.f;
  for (int d = lane; d < DIM; d += 64) {
    float xv = xr[d];
    xbr[d] = f2bf(xv);
    const f32x4* wr = reinterpret_cast<const f32x4*>(Wg + (size_t)d * NEXP);
    f32x4 w0 = wr[0], w1 = wr[1];
    acc[0] += xv * w0.x; acc[1] += xv * w0.y; acc[2] += xv * w0.z; acc[3] += xv * w0.w;
    acc[4] += xv * w1.x; acc[5] += xv * w1.y; acc[6] += xv * w1.z; acc[7] += xv * w1.w;
  }
#pragma unroll
  for (int e = 0; e < NEXP; e++) {
#pragma unroll
    for (int off = 32; off > 0; off >>= 1)
      acc[e] += __shfl_xor(acc[e], off, 64);
  }
  if (lane == 0) {
    float s[NEXP];
#pragma unroll
    for (int e = 0; e < NEXP; e++) s[e] = acc[e] + bg[e];
    int i0 = 0; float b0 = s[0];
#pragma unroll
    for (int e = 1; e < NEXP; e++) if (s[e] > b0) { b0 = s[e]; i0 = e; }
    int i1 = -1; float b1v = -3.4e38f;
#pragma unroll
    for (int e = 0; e < NEXP; e++) if (e != i0 && s[e] > b1v) { b1v = s[e]; i1 = e; }
    float e1 = __expf(b1v - b0);
    float inv = 1.f / (1.f + e1);
    topk_idx[t*2]   = i0;  topk_idx[t*2+1] = i1;
    topk_w[t*2]     = inv; topk_w[t*2+1]   = e1 * inv;
    atomicAdd(&expert_count[i0], 1);
    atomicAdd(&expert_count[i1], 1);
  }
}

// ---------------- routing: scan + two tile tables + deterministic scatter ----------
__global__ void route_kernel(const int* __restrict__ expert_count,
                             int* __restrict__ expert_offset,
                             int* __restrict__ table1, int* __restrict__ nt1,
                             int* __restrict__ table2, int* __restrict__ nt2,
                             const int* __restrict__ topk_idx,
                             const float* __restrict__ topk_w,
                             int* __restrict__ pair_token, float* __restrict__ pair_w)
{
  __shared__ int soff[NEXP];
  if (threadIdx.x == 0) {
    int off = 0, a = 0, b = 0;
    for (int e = 0; e < NEXP; e++) {
      expert_offset[e] = off; soff[e] = off;
      int c = expert_count[e];
      for (int r = 0; r < c; r += 256) {
        table1[a*4+0] = e; table1[a*4+1] = off + r;
        table1[a*4+2] = (c - r) < 256 ? (c - r) : 256; a++;
      }
      for (int r = 0; r < c; r += 128) {
        table2[b*4+0] = e; table2[b*4+1] = off + r;
        table2[b*4+2] = (c - r) < 128 ? (c - r) : 128; b++;
      }
      off += c;
    }
    expert_offset[NEXP] = off;
    *nt1 = a; *nt2 = b;
  }
  __syncthreads();
  const int e = threadIdx.x >> 6;
  const int lane = threadIdx.x & 63;
  int base = soff[e];
  for (int a0 = 0; a0 < NPOS; a0 += 64) {
    int a = a0 + lane;
    int idx = topk_idx[a];
    bool f = (idx == e);
    unsigned long long m = __ballot(f);
    if (f) {
      int pos = base + __popcll(m & ((1ull << lane) - 1ull));
      pair_token[pos] = a >> 1;
      pair_w[pos]     = topk_w[a];
    }
    base += __popcll(m);
  }
}

// helper: build bf16x8 MFMA operand from two us4 LDS reads
__device__ __forceinline__ bf16x8 mk8(us4 lo, us4 hi) {
  us8 u = __builtin_shufflevector(lo, hi, 0, 1, 2, 3, 4, 5, 6, 7);
  return __builtin_bit_cast(bf16x8, u);
}

// ============ K3: FFN1 — in-kernel W1 f32 staging (reg-transpose), no Wt1 ==========
// BM=256, BN=128, BK=32, 512 thr. A: xb gather via gload_lds (linear [row][32]).
// B: W1 native [k][n] f32 -> 4x f32x2 loads -> cvt -> 2x ds_write_b64 at [n][k0..k0+3]
//    (register 4x2 transpose), LDS [128][36]. T14 split: B-loads issued before
//    COMPUTE(t), cvt+write after (HBM latency hides under MFMA).
__global__ __launch_bounds__(512) void ffn1_kernel(
    const unsigned short* __restrict__ xb, const float* __restrict__ W1,
    const float* __restrict__ b1, const int* __restrict__ pair_token,
    const int* __restrict__ table1, const int* __restrict__ nt1,
    unsigned short* __restrict__ h_buf)
{
  __shared__ __align__(16) char smem[52224];   // A 2x16K | B 2x9216 | tok 1K
  int* tok = (int*)(smem + 51200);

  int wg = blockIdx.x;                 // 1280 % 8 == 0, bijective XCD swizzle
  wg = (wg & 7) * (G1/8) + (wg >> 3);
  const int mt = wg % MAXT1;
  const int n0 = (wg / MAXT1) * 128;
  if (mt >= *nt1) return;
  const int e = table1[mt*4+0], row_start = table1[mt*4+1], rows_valid = table1[mt*4+2];

  const int tid = threadIdx.x;
  if (tid < 256) tok[tid] = pair_token[row_start + (tid < rows_valid ? tid : 0)];
  __syncthreads();

  const int w = tid >> 6, l = tid & 63;
  // A staging: row = tid>>2 (0..127), 16B col = (tid&3)*8 shorts
  const int arow = tid >> 2;
  const int aq8  = (tid & 3) * 8;
  const unsigned short* pA0 = xb + (size_t)tok[arow]       * DIM + aq8;
  const unsigned short* pA1 = xb + (size_t)tok[128 + arow] * DIM + aq8;
  const int wbase = w * 1024;
  // B staging: n2 = (tid&63)*2, k0 = (tid>>6)*4
  const int bn2 = (tid & 63) * 2;
  const int bk0 = (tid >> 6) * 4;
  const float* W1e = W1 + (size_t)e * DIM * HID + n0 + bn2;

  f32x4 acc[4][4];
#pragma unroll
  for (int m = 0; m < 4; m++)
#pragma unroll
    for (int n = 0; n < 4; n++) acc[m][n] = (f32x4){0.f, 0.f, 0.f, 0.f};

  const int wr = w >> 1, wc = w & 1;
  const int frow = l & 15, kb = (l >> 4) * 8;

  f32x2 vb[4];
  auto B_LOAD = [&](int kt) {
    const float* p = W1e + (size_t)(kt + bk0) * HID;
#pragma unroll
    for (int i = 0; i < 4; i++)
      vb[i] = *reinterpret_cast<const f32x2*>(p + (size_t)i * HID);
  };
  auto A_STAGE = [&](int kt, int buf) {
    char* Ab = smem + buf * 16384;
    gload16(pA0 + kt, Ab + wbase);
    gload16(pA1 + kt, Ab + 8192 + wbase);
  };
  auto B_WRITE = [&](int buf) {
    unsigned short* Bb = (unsigned short*)(smem + 32768 + buf * 9216);
    us4 c0 = { f2bf(vb[0].x), f2bf(vb[1].x), f2bf(vb[2].x), f2bf(vb[3].x) };
    us4 c1 = { f2bf(vb[0].y), f2bf(vb[1].y), f2bf(vb[2].y), f2bf(vb[3].y) };
    *reinterpret_cast<us4*>(&Bb[(bn2    ) * BSTR + bk0]) = c0;
    *reinterpret_cast<us4*>(&Bb[(bn2 + 1) * BSTR + bk0]) = c1;
  };
  auto COMPUTE = [&](int buf) {
    const unsigned short* A = (const unsigned short*)(smem + buf * 16384);
    const unsigned short* B = (const unsigned short*)(smem + 32768 + buf * 9216);
    bf16x8 af[4], bfr[4];
#pragma unroll
    for (int m = 0; m < 4; m++)
      af[m] = *reinterpret_cast<const bf16x8*>(A + (wr*64 + m*16 + frow) * BK + kb);
#pragma unroll
    for (int n = 0; n < 4; n++) {
      const int row = wc*64 + n*16 + frow;
      us4 lo = *reinterpret_cast<const us4*>(&B[row * BSTR + kb]);
      us4 hi = *reinterpret_cast<const us4*>(&B[row * BSTR + kb + 4]);
      bfr[n] = mk8(lo, hi);
    }
    WAITL();
#pragma unroll
    for (int m = 0; m < 4; m++)
#pragma unroll
      for (int n = 0; n < 4; n++)
        acc[m][n] = __builtin_amdgcn_mfma_f32_16x16x32_bf16(af[m], bfr[n], acc[m][n], 0, 0, 0);
  };

  // prologue: tile 0
  B_LOAD(0);
  A_STAGE(0, 0);
  B_WRITE(0);
  WAITV0(); WAITL(); BAR();

  int cur = 0;
#pragma unroll 1
  for (int t = 0; t < DIM/BK; ++t) {
    const bool more = (t + 1) < DIM/BK;
    if (more) { B_LOAD((t+1)*BK); A_STAGE((t+1)*BK, cur ^ 1); }
    COMPUTE(cur);
    if (more) {
      B_WRITE(cur ^ 1);
      WAITV0(); WAITL(); BAR();
    }
    cur ^= 1;
  }

  const int crow = (l >> 4) * 4;
  const int ccol = l & 15;
#pragma unroll
  for (int n = 0; n < 4; n++) {
    const int cg = n0 + wc*64 + n*16 + ccol;
    const float bias = b1[(size_t)e * HID + cg];
#pragma unroll
    for (int m = 0; m < 4; m++) {
#pragma unroll
      for (int j = 0; j < 4; j++) {
        int r = wr*64 + m*16 + crow + j;
        if (r < rows_valid)
          h_buf[(size_t)(row_start + r) * HID + cg] = f2bf(fmaxf(acc[m][n][j] + bias, 0.f));
      }
    }
  }
}

// ============ K4: FFN2 — in-kernel W2 f32 staging, full K, atomic combine ==========
// BM=128, BN=128, BK=32, 256 thr. n0-fast XCD-chunked order (h-panel L2 reuse).
__global__ __launch_bounds__(256) void ffn2_kernel(
    const unsigned short* __restrict__ h_buf, const float* __restrict__ W2,
    const float* __restrict__ b2, const int* __restrict__ pair_token,
    const float* __restrict__ pair_w, const int* __restrict__ table2,
    const int* __restrict__ nt2, float* __restrict__ out)
{
  __shared__ __align__(16) char smem[34816];   // A 2x8K | B 2x9216

  const int bx = blockIdx.x;                  // 576 = 8 * 72
  const int j  = (bx & 7) * (G2 / 8) + (bx >> 3);
  const int mt = j >> 3;                      // n0-fast within XCD chunk
  const int n0 = (j & 7) * 128;
  if (mt >= *nt2) return;
  const int e = table2[mt*4+0], row_start = table2[mt*4+1], rows_valid = table2[mt*4+2];

  const int tid = threadIdx.x;
  const int w = tid >> 6, l = tid & 63;
  const int arow = tid >> 2;                  // 0..63
  const int aq8  = (tid & 3) * 8;
  int ar0 = row_start + arow;      if (ar0 > NPOS - 1) ar0 = NPOS - 1;
  int ar1 = row_start + 64 + arow; if (ar1 > NPOS - 1) ar1 = NPOS - 1;
  const unsigned short* pA0 = h_buf + (size_t)ar0 * HID + aq8;
  const unsigned short* pA1 = h_buf + (size_t)ar1 * HID + aq8;
  const int wbase = w * 1024;

  const int bn2 = (tid & 63) * 2;
  const int bk0 = (tid >> 6) * 4;             // 0..12; also bk0+16
  const float* W2e = W2 + (size_t)e * HID * DIM + n0 + bn2;

  f32x4 acc[4][4];
#pragma unroll
  for (int m = 0; m < 4; m++)
#pragma unroll
    for (int n = 0; n < 4; n++) acc[m][n] = (f32x4){0.f, 0.f, 0.f, 0.f};

  const int wr = w >> 1, wc = w & 1;
  const int frow = l & 15, kb = (l >> 4) * 8;

  f32x2 vb[8];
  auto B_LOAD = [&](int kt) {
    const float* p0 = W2e + (size_t)(kt + bk0) * DIM;
    const float* p1 = W2e + (size_t)(kt + bk0 + 16) * DIM;
#pragma unroll
    for (int i = 0; i < 4; i++) {
      vb[i]     = *reinterpret_cast<const f32x2*>(p0 + (size_t)i * DIM);
      vb[4 + i] = *reinterpret_cast<const f32x2*>(p1 + (size_t)i * DIM);
    }
  };
  auto A_STAGE = [&](int kt, int buf) {
    char* Ab = smem + buf * 8192;
    gload16(pA0 + kt, Ab + wbase);
    gload16(pA1 + kt, Ab + 4096 + wbase);
  };
  auto B_WRITE = [&](int buf) {
    unsigned short* Bb = (unsigned short*)(smem + 16384 + buf * 9216);
    us4 c0 = { f2bf(vb[0].x), f2bf(vb[1].x), f2bf(vb[2].x), f2bf(vb[3].x) };
    us4 c1 = { f2bf(vb[0].y), f2bf(vb[1].y), f2bf(vb[2].y), f2bf(vb[3].y) };
    us4 c2 = { f2bf(vb[4].x), f2bf(vb[5].x), f2bf(vb[6].x), f2bf(vb[7].x) };
    us4 c3 = { f2bf(vb[4].y), f2bf(vb[5].y), f2bf(vb[6].y), f2bf(vb[7].y) };
    *reinterpret_cast<us4*>(&Bb[(bn2    ) * BSTR + bk0     ]) = c0;
    *reinterpret_cast<us4*>(&Bb[(bn2 + 1) * BSTR + bk0     ]) = c1;
    *reinterpret_cast<us4*>(&Bb[(bn2    ) * BSTR + bk0 + 16]) = c2;
    *reinterpret_cast<us4*>(&Bb[(bn2 + 1) * BSTR + bk0 + 16]) = c3;
  };
  auto COMPUTE = [&](int buf) {
    const unsigned short* A = (const unsigned short*)(smem + buf * 8192);
    const unsigned short* B = (const unsigned short*)(smem + 16384 + buf * 9216);
    bf16x8 af[4], bfr[4];
#pragma unroll
    for (int m = 0; m < 4; m++)
      af[m] = *reinterpret_cast<const bf16x8*>(A + (wr*64 + m*16 + frow) * BK + kb);
#pragma unroll
    for (int n = 0; n < 4; n++) {
      const int row = wc*64 + n*16 + frow;
      us4 lo = *reinterpret_cast<const us4*>(&B[row * BSTR + kb]);
      us4 hi = *reinterpret_cast<const us4*>(&B[row * BSTR + kb + 4]);
      bfr[n] = mk8(lo, hi);
    }
    WAITL();
#pragma unroll
    for (int m = 0; m < 4; m++)
#pragma unroll
      for (int n = 0; n < 4; n++)
        acc[m][n] = __builtin_amdgcn_mfma_f32_16x16x32_bf16(af[m], bfr[n], acc[m][n], 0, 0, 0);
  };

  B_LOAD(0);
  A_STAGE(0, 0);
  B_WRITE(0);
  WAITV0(); WAITL(); BAR();

  int cur = 0;
#pragma unroll 1
  for (int t = 0; t < HID/BK; ++t) {
    const bool more = (t + 1) < HID/BK;
    if (more) { B_LOAD((t+1)*BK); A_STAGE((t+1)*BK, cur ^ 1); }
    COMPUTE(cur);
    if (more) {
      B_WRITE(cur ^ 1);
      WAITV0(); WAITL(); BAR();
    }
    cur ^= 1;
  }

  const int crow = (l >> 4) * 4;
  const int ccol = l & 15;
  float bias[4];
#pragma unroll
  for (int n = 0; n < 4; n++)
    bias[n] = b2[(size_t)e * DIM + n0 + wc*64 + n*16 + ccol];

#pragma unroll
  for (int m = 0; m < 4; m++) {
#pragma unroll
    for (int j2 = 0; j2 < 4; j2++) {
      int r = wr*64 + m*16 + crow + j2;
      if (r < rows_valid) {
        int pos = row_start + r;
        int t   = pair_token[pos];
        float wv = pair_w[pos];
        float* orow = out + (size_t)t * DIM;
#pragma unroll
        for (int n = 0; n < 4; n++)
          atomicAdd(&orow[n0 + wc*64 + n*16 + ccol], (acc[m][n][j2] + bias[n]) * wv);
      }
    }
  }
}

extern "C" void kernel_launch(void* const* d_in, const int* in_sizes, int n_in,
                              void* d_out, int out_size, void* d_ws, size_t ws_size,
                              hipStream_t stream) {
  const float* x  = (const float*)d_in[0];
  const float* Wg = (const float*)d_in[1];
  const float* bg = (const float*)d_in[2];
  const float* W1 = (const float*)d_in[3];
  const float* b1 = (const float*)d_in[4];
  const float* W2 = (const float*)d_in[5];
  const float* b2 = (const float*)d_in[6];
  float* out = (float*)d_out;

  char* ws = (char*)d_ws;
  const size_t MB = 1024 * 1024;
  int*   expert_count  = (int*)(ws + 0);
  int*   nt1           = (int*)(ws + 64);
  int*   nt2           = (int*)(ws + 68);
  int*   expert_offset = (int*)(ws + 128);
  int*   table1        = (int*)(ws + 1024);
  int*   table2        = (int*)(ws + 2048);
  int*   topk_idx      = (int*)(ws + 4096);
  float* topk_w        = (float*)(ws + 4096 + 32768);
  int*   pair_token    = (int*)(ws + 4096 + 65536);
  float* pair_w        = (float*)(ws + 4096 + 98304);
  unsigned short* xb   = (unsigned short*)(ws + 1*MB);    //  8 MiB
  unsigned short* h    = (unsigned short*)(ws + 9*MB);    // 64 MiB — total 73 MiB

  hipMemsetAsync(ws, 0, 256, stream);
  hipMemsetAsync(d_out, 0, (size_t)N_TOK * DIM * sizeof(float), stream);

  // K1: gate + x->bf16 (small)
  gate_kernel<<<N_TOK/4, 256, 0, stream>>>(x, Wg, bg, topk_idx, topk_w,
                                           expert_count, xb);
  // K2: routing
  route_kernel<<<1, 512, 0, stream>>>(expert_count, expert_offset, table1, nt1,
                                      table2, nt2, topk_idx, topk_w,
                                      pair_token, pair_w);
  // K3: ffn1 — consumes W1 f32 directly (reg-transpose staging)
  ffn1_kernel<<<G1, 512, 0, stream>>>(xb, W1, b1, pair_token, table1, nt1, h);
  // K4: ffn2 — consumes W2 f32 directly, atomic combine
  ffn2_kernel<<<G2, 256, 0, stream>>>(h, W2, b2, pair_token, pair_w, table2, nt2, out);
}

// Round 19
// 464.985 us; speedup vs baseline: 1.2776x; 1.2776x over previous
//
#include <hip/hip_runtime.h>
#include <hip/hip_bf16.h>

#define N_TOK 4096
#define DIM   1024
#define HID   4096
#define NEXP  8
#define NPOS  8192

#define BK    32
#define MAXT1 40                     // BM=256 m-tiles max
#define MAXT2 72                     // BM=128 m-tiles max
#define G1    (MAXT1 * (HID/128))    // 1280 ffn1 blocks
#define G2    (MAXT2 * (DIM/128))    // 576 ffn2 blocks (full K, n0-fast order)
#define T1J   8192                   // W1 transpose 64x64 tiles
#define T2J   8192                   // W2 transpose 64x64 tiles

typedef float  f32x4  __attribute__((ext_vector_type(4)));
typedef __bf16 bf16x8 __attribute__((ext_vector_type(8)));
typedef unsigned short us8 __attribute__((ext_vector_type(8)));

__device__ __forceinline__ unsigned short f2bf(float f) {
  __hip_bfloat16 h = __float2bfloat16(f);
  return *reinterpret_cast<unsigned short*>(&h);
}
__device__ __forceinline__ void gload16(const void* g, void* l) {
  __builtin_amdgcn_global_load_lds(
      (const __attribute__((address_space(1))) unsigned int*)g,
      (__attribute__((address_space(3))) unsigned int*)l, 16, 0, 0);
}
#define BAR()    __builtin_amdgcn_s_barrier()
#define WAITV(n) asm volatile("s_waitcnt vmcnt(" #n ")" ::: "memory")
#define WAITL()  asm volatile("s_waitcnt lgkmcnt(0)" ::: "memory")

// ============ K1: gate (+x->bf16) fused with W1 transpose ============
__global__ __launch_bounds__(256) void gate_t1_kernel(
    const float* __restrict__ x, const float* __restrict__ Wg,
    const float* __restrict__ bg, int* __restrict__ topk_idx,
    float* __restrict__ topk_w, int* __restrict__ expert_count,
    unsigned short* __restrict__ xb,
    const float* __restrict__ W1, unsigned short* __restrict__ Wt1)
{
  __shared__ float S[64][67];
  const int tid = threadIdx.x;
  const int bx = blockIdx.x;

  if (bx >= N_TOK/4) {               // ---- W1 transpose: [1024][4096] -> [4096][1024]
    const int tj = bx - N_TOK/4;
    const int e  = tj >> 10;
    const int rem = tj & 1023;
    const int r0 = (rem >> 6) * 64;  // over DIM
    const int c0 = (rem & 63) * 64;  // over HID
    const float* s = W1 + (size_t)e * DIM * HID;
    unsigned short* d = Wt1 + (size_t)e * DIM * HID;
    {
      const int rr = tid >> 2, cc = (tid & 3) * 16;
      const float* sp = s + (size_t)(r0 + rr) * HID + c0 + cc;
#pragma unroll
      for (int j = 0; j < 4; j++) {
        f32x4 v = *reinterpret_cast<const f32x4*>(sp + j * 4);
        S[rr][cc + j*4 + 0] = v.x;
        S[rr][cc + j*4 + 1] = v.y;
        S[rr][cc + j*4 + 2] = v.z;
        S[rr][cc + j*4 + 3] = v.w;
      }
    }
    __syncthreads();
    {
      const int hh = tid >> 2, dbase = (tid & 3) * 16;
      us8 o0, o1;
#pragma unroll
      for (int i = 0; i < 8; i++) o0[i] = f2bf(S[dbase + i][hh]);
#pragma unroll
      for (int i = 0; i < 8; i++) o1[i] = f2bf(S[dbase + 8 + i][hh]);
      unsigned short* dp = d + (size_t)(c0 + hh) * DIM + r0 + dbase;
      *reinterpret_cast<us8*>(dp)     = o0;
      *reinterpret_cast<us8*>(dp + 8) = o1;
    }
    return;
  }

  // ---- gate role ----
  const int wave = tid >> 6, lane = tid & 63;
  const int t = bx * 4 + wave;
  const float* xr = x + (size_t)t * DIM;
  unsigned short* xbr = xb + (size_t)t * DIM;

  float acc[NEXP];
#pragma unroll
  for (int e = 0; e < NEXP; e++) acc[e] = 0.f;
  for (int d = lane; d < DIM; d += 64) {
    float xv = xr[d];
    xbr[d] = f2bf(xv);
    const f32x4* wr = reinterpret_cast<const f32x4*>(Wg + (size_t)d * NEXP);
    f32x4 w0 = wr[0], w1 = wr[1];
    acc[0] += xv * w0.x; acc[1] += xv * w0.y; acc[2] += xv * w0.z; acc[3] += xv * w0.w;
    acc[4] += xv * w1.x; acc[5] += xv * w1.y; acc[6] += xv * w1.z; acc[7] += xv * w1.w;
  }
#pragma unroll
  for (int e = 0; e < NEXP; e++) {
#pragma unroll
    for (int off = 32; off > 0; off >>= 1)
      acc[e] += __shfl_xor(acc[e], off, 64);
  }
  if (lane == 0) {
    float s[NEXP];
#pragma unroll
    for (int e = 0; e < NEXP; e++) s[e] = acc[e] + bg[e];
    int i0 = 0; float b0 = s[0];
#pragma unroll
    for (int e = 1; e < NEXP; e++) if (s[e] > b0) { b0 = s[e]; i0 = e; }
    int i1 = -1; float b1v = -3.4e38f;
#pragma unroll
    for (int e = 0; e < NEXP; e++) if (e != i0 && s[e] > b1v) { b1v = s[e]; i1 = e; }
    float e1 = __expf(b1v - b0);
    float inv = 1.f / (1.f + e1);
    topk_idx[t*2]   = i0;  topk_idx[t*2+1] = i1;
    topk_w[t*2]     = inv; topk_w[t*2+1]   = e1 * inv;
    atomicAdd(&expert_count[i0], 1);
    atomicAdd(&expert_count[i1], 1);
  }
}

// ---------------- routing: scan + two tile tables + deterministic scatter ----------
__global__ void route_kernel(const int* __restrict__ expert_count,
                             int* __restrict__ expert_offset,
                             int* __restrict__ table1, int* __restrict__ nt1,
                             int* __restrict__ table2, int* __restrict__ nt2,
                             const int* __restrict__ topk_idx,
                             const float* __restrict__ topk_w,
                             int* __restrict__ pair_token, float* __restrict__ pair_w)
{
  __shared__ int soff[NEXP];
  if (threadIdx.x == 0) {
    int off = 0, a = 0, b = 0;
    for (int e = 0; e < NEXP; e++) {
      expert_offset[e] = off; soff[e] = off;
      int c = expert_count[e];
      for (int r = 0; r < c; r += 256) {
        table1[a*4+0] = e; table1[a*4+1] = off + r;
        table1[a*4+2] = (c - r) < 256 ? (c - r) : 256; a++;
      }
      for (int r = 0; r < c; r += 128) {
        table2[b*4+0] = e; table2[b*4+1] = off + r;
        table2[b*4+2] = (c - r) < 128 ? (c - r) : 128; b++;
      }
      off += c;
    }
    expert_offset[NEXP] = off;
    *nt1 = a; *nt2 = b;
  }
  __syncthreads();
  const int e = threadIdx.x >> 6;
  const int lane = threadIdx.x & 63;
  int base = soff[e];
  for (int a0 = 0; a0 < NPOS; a0 += 64) {
    int a = a0 + lane;
    int idx = topk_idx[a];
    bool f = (idx == e);
    unsigned long long m = __ballot(f);
    if (f) {
      int pos = base + __popcll(m & ((1ull << lane) - 1ull));
      pair_token[pos] = a >> 1;
      pair_w[pos]     = topk_w[a];
    }
    base += __popcll(m);
  }
}

// ---------------- standalone transpose (fallback path only) ----------------
__global__ __launch_bounds__(256) void transpose_kernel(const float* __restrict__ src,
                                                        unsigned short* __restrict__ dst,
                                                        int R, int C)
{
  __shared__ float S[64][67];
  const int e = blockIdx.z;
  const float* s = src + (size_t)e * R * C;
  unsigned short* d = dst + (size_t)e * R * C;
  const int r0 = blockIdx.y * 64, c0 = blockIdx.x * 64;
  const int tid = threadIdx.x;
  {
    const int rr = tid >> 2, cc = (tid & 3) * 16;
    const float* sp = s + (size_t)(r0 + rr) * C + c0 + cc;
#pragma unroll
    for (int j = 0; j < 4; j++) {
      f32x4 v = *reinterpret_cast<const f32x4*>(sp + j * 4);
      S[rr][cc + j*4 + 0] = v.x;
      S[rr][cc + j*4 + 1] = v.y;
      S[rr][cc + j*4 + 2] = v.z;
      S[rr][cc + j*4 + 3] = v.w;
    }
  }
  __syncthreads();
  {
    const int hh = tid >> 2, dbase = (tid & 3) * 16;
    us8 o0, o1;
#pragma unroll
    for (int i = 0; i < 8; i++) o0[i] = f2bf(S[dbase + i][hh]);
#pragma unroll
    for (int i = 0; i < 8; i++) o1[i] = f2bf(S[dbase + 8 + i][hh]);
    unsigned short* dp = d + (size_t)(c0 + hh) * R + r0 + dbase;
    *reinterpret_cast<us8*>(dp)     = o0;
    *reinterpret_cast<us8*>(dp + 8) = o1;
  }
}

// ============ K3: FFN1 (BM=256 BN=128 BK=32, 512thr, dbuf) + fused W2 transpose ====
__global__ __launch_bounds__(512) void ffn1_t2_kernel(
    const unsigned short* __restrict__ xb, const unsigned short* __restrict__ Wt1,
    const float* __restrict__ b1, const int* __restrict__ pair_token,
    const int* __restrict__ table1, const int* __restrict__ nt1,
    unsigned short* __restrict__ h_buf,
    const float* __restrict__ W2, unsigned short* __restrict__ Wt2, int t2jobs)
{
  __shared__ __align__(16) char smem[50176];
  const int tid = threadIdx.x;
  const int bx = blockIdx.x;

  if (bx >= G1) {                    // ---- W2 transpose: [4096][1024] -> [1024][4096]
    const int tj = bx - G1;
    if (tj >= t2jobs) return;
    float (*S)[67] = (float(*)[67])smem;
    const int e   = tj >> 10;
    const int rem = tj & 1023;
    const int r0 = (rem >> 4) * 64;  // over HID (64 tiles)
    const int c0 = (rem & 15) * 64;  // over DIM (16 tiles)
    const float* s = W2 + (size_t)e * HID * DIM;
    unsigned short* d = Wt2 + (size_t)e * HID * DIM;
    {
      const int rr = tid >> 3, cc = (tid & 7) * 8;   // 512 thr: 8 f32 each
      const float* sp = s + (size_t)(r0 + rr) * DIM + c0 + cc;
      f32x4 v0 = *reinterpret_cast<const f32x4*>(sp);
      f32x4 v1 = *reinterpret_cast<const f32x4*>(sp + 4);
      S[rr][cc+0] = v0.x; S[rr][cc+1] = v0.y; S[rr][cc+2] = v0.z; S[rr][cc+3] = v0.w;
      S[rr][cc+4] = v1.x; S[rr][cc+5] = v1.y; S[rr][cc+6] = v1.z; S[rr][cc+7] = v1.w;
    }
    __syncthreads();
    {
      const int hh = tid >> 3, dbase = (tid & 7) * 8;
      us8 o;
#pragma unroll
      for (int i = 0; i < 8; i++) o[i] = f2bf(S[dbase + i][hh]);
      *reinterpret_cast<us8*>(d + (size_t)(c0 + hh) * HID + r0 + dbase) = o;
    }
    return;
  }

  // ---- ffn1 role ----
  int wg = bx;                       // 1280 % 8 == 0, bijective
  wg = (wg & 7) * (G1/8) + (wg >> 3);
  const int mt = wg % MAXT1;
  const int n0 = (wg / MAXT1) * 128;
  if (mt >= *nt1) return;
  const int e = table1[mt*4+0], row_start = table1[mt*4+1], rows_valid = table1[mt*4+2];

  unsigned short* As0 = (unsigned short*)smem;          // 256x32 = 16KB
  unsigned short* As1 = As0 + 8192;
  unsigned short* Bs0 = As1 + 8192;                     // 128x32 = 8KB
  unsigned short* Bs1 = Bs0 + 4096;
  int* tok = (int*)(smem + 49152);

  if (tid < 256) tok[tid] = pair_token[row_start + (tid < rows_valid ? tid : 0)];
  __syncthreads();

  const int w = tid >> 6, l = tid & 63;
  const int srow = w * 16 + (l >> 2);      // 0..127
  const int q8   = (l & 3) * 8;

  const unsigned short* pA0 = xb + (size_t)tok[srow] * DIM + q8;
  const unsigned short* pA1 = xb + (size_t)tok[128 + srow] * DIM + q8;
  const unsigned short* We  = Wt1 + (size_t)e * HID * DIM;
  const unsigned short* pB  = We + (size_t)(n0 + srow) * DIM + q8;
  const int wbase = w * 1024;

  f32x4 acc[4][4];
#pragma unroll
  for (int m = 0; m < 4; m++)
#pragma unroll
    for (int n = 0; n < 4; n++) acc[m][n] = (f32x4){0.f, 0.f, 0.f, 0.f};

  const int wr = w >> 1, wc = w & 1;
  const int frow = l & 15, kb = (l >> 4) * 8;

  auto STAGE = [&](int kt, unsigned short* A, unsigned short* B) {
    gload16(pA0 + kt, (char*)A + wbase);
    gload16(pA1 + kt, (char*)A + 8192 + wbase);
    gload16(pB  + kt, (char*)B + wbase);
  };
  auto COMPUTE = [&](const unsigned short* A, const unsigned short* B) {
    bf16x8 af[4], bfr[4];
#pragma unroll
    for (int m = 0; m < 4; m++)
      af[m] = *reinterpret_cast<const bf16x8*>(A + (wr*64 + m*16 + frow) * BK + kb);
#pragma unroll
    for (int n = 0; n < 4; n++)
      bfr[n] = *reinterpret_cast<const bf16x8*>(B + (wc*64 + n*16 + frow) * BK + kb);
#pragma unroll
    for (int m = 0; m < 4; m++)
#pragma unroll
      for (int n = 0; n < 4; n++)
        acc[m][n] = __builtin_amdgcn_mfma_f32_16x16x32_bf16(af[m], bfr[n], acc[m][n], 0, 0, 0);
    WAITL();
    BAR();
  };

  STAGE(0, As0, Bs0);
  int ks = BK;
  for (int i = 0; i < 15; i++) {           // 32 K-steps
    STAGE(ks, As1, Bs1); ks += BK;
    WAITV(3); BAR();
    COMPUTE(As0, Bs0);
    STAGE(ks, As0, Bs0); ks += BK;
    WAITV(3); BAR();
    COMPUTE(As1, Bs1);
  }
  STAGE(ks, As1, Bs1);
  WAITV(3); BAR();
  COMPUTE(As0, Bs0);
  WAITV(0); BAR();
  COMPUTE(As1, Bs1);

  const int crow = (l >> 4) * 4;
  const int ccol = l & 15;
#pragma unroll
  for (int n = 0; n < 4; n++) {
    const int cg = n0 + wc*64 + n*16 + ccol;
    const float bias = b1[(size_t)e * HID + cg];
#pragma unroll
    for (int m = 0; m < 4; m++) {
#pragma unroll
      for (int j = 0; j < 4; j++) {
        int r = wr*64 + m*16 + crow + j;
        if (r < rows_valid)
          h_buf[(size_t)(row_start + r) * HID + cg] = f2bf(fmaxf(acc[m][n][j] + bias, 0.f));
      }
    }
  }
}

// ============ K4: FFN2 (BM=128 BN=128 BK=32, 256thr, dbuf), full K, atomic ==========
// n0-fast XCD-chunked order: each XCD gets consecutive jobs {same mt, all 8 n0}
// so the 1MB A-panel (h rows) stays L2-resident across its 8 uses.
__global__ __launch_bounds__(256) void ffn2_kernel(
    const unsigned short* __restrict__ h_buf, const unsigned short* __restrict__ Wt2,
    const float* __restrict__ b2, const int* __restrict__ pair_token,
    const float* __restrict__ pair_w, const int* __restrict__ table2,
    const int* __restrict__ nt2, float* __restrict__ out)
{
  const int bx = blockIdx.x;                  // 576 = 8 * 72
  const int j  = (bx & 7) * (G2 / 8) + (bx >> 3);
  const int mt = j >> 3;                      // 0..71 (n0-fast within XCD chunk)
  const int n0 = (j & 7) * 128;
  if (mt >= *nt2) return;
  const int e = table2[mt*4+0], row_start = table2[mt*4+1], rows_valid = table2[mt*4+2];

  __shared__ __align__(16) unsigned short As0[128*BK], As1[128*BK];
  __shared__ __align__(16) unsigned short Bs0[128*BK], Bs1[128*BK];

  const int tid = threadIdx.x;
  const int w = tid >> 6, l = tid & 63;
  const int srow = w * 16 + (l >> 2);        // 0..63
  const int q8   = (l & 3) * 8;

  int ar0 = row_start + srow;       if (ar0 > NPOS - 1) ar0 = NPOS - 1;
  int ar1 = row_start + 64 + srow;  if (ar1 > NPOS - 1) ar1 = NPOS - 1;

  const unsigned short* pA0 = h_buf + (size_t)ar0 * HID + q8;
  const unsigned short* pA1 = h_buf + (size_t)ar1 * HID + q8;
  const unsigned short* We  = Wt2 + (size_t)e * DIM * HID;
  const unsigned short* pB0 = We + (size_t)(n0 + srow) * HID + q8;
  const unsigned short* pB1 = We + (size_t)(n0 + 64 + srow) * HID + q8;
  const int wbase = w * 1024;

  f32x4 acc[4][4];
#pragma unroll
  for (int m = 0; m < 4; m++)
#pragma unroll
    for (int n = 0; n < 4; n++) acc[m][n] = (f32x4){0.f, 0.f, 0.f, 0.f};

  const int wr = w >> 1, wc = w & 1;
  const int frow = l & 15, kb = (l >> 4) * 8;

  auto STAGE = [&](int kt, unsigned short* A, unsigned short* B) {
    gload16(pA0 + kt, (char*)A + wbase);
    gload16(pA1 + kt, (char*)A + 4096 + wbase);
    gload16(pB0 + kt, (char*)B + wbase);
    gload16(pB1 + kt, (char*)B + 4096 + wbase);
  };
  auto COMPUTE = [&](const unsigned short* A, const unsigned short* B) {
    bf16x8 af[4], bfr[4];
#pragma unroll
    for (int m = 0; m < 4; m++)
      af[m] = *reinterpret_cast<const bf16x8*>(A + (wr*64 + m*16 + frow) * BK + kb);
#pragma unroll
    for (int n = 0; n < 4; n++)
      bfr[n] = *reinterpret_cast<const bf16x8*>(B + (wc*64 + n*16 + frow) * BK + kb);
#pragma unroll
    for (int m = 0; m < 4; m++)
#pragma unroll
      for (int n = 0; n < 4; n++)
        acc[m][n] = __builtin_amdgcn_mfma_f32_16x16x32_bf16(af[m], bfr[n], acc[m][n], 0, 0, 0);
    WAITL();
    BAR();
  };

  STAGE(0, As0, Bs0);
  int ks = BK;
  for (int i = 0; i < 63; i++) {             // 128 K-steps (K=4096)
    STAGE(ks, As1, Bs1); ks += BK;
    WAITV(4); BAR();
    COMPUTE(As0, Bs0);
    STAGE(ks, As0, Bs0); ks += BK;
    WAITV(4); BAR();
    COMPUTE(As1, Bs1);
  }
  STAGE(ks, As1, Bs1);
  WAITV(4); BAR();
  COMPUTE(As0, Bs0);
  WAITV(0); BAR();
  COMPUTE(As1, Bs1);

  const int crow = (l >> 4) * 4;
  const int ccol = l & 15;
  float bias[4];
#pragma unroll
  for (int n = 0; n < 4; n++)
    bias[n] = b2[(size_t)e * DIM + n0 + wc*64 + n*16 + ccol];

#pragma unroll
  for (int m = 0; m < 4; m++) {
#pragma unroll
    for (int j2 = 0; j2 < 4; j2++) {
      int r = wr*64 + m*16 + crow + j2;
      if (r < rows_valid) {
        int pos = row_start + r;
        int t   = pair_token[pos];
        float wv = pair_w[pos];
        float* orow = out + (size_t)t * DIM;
#pragma unroll
        for (int n = 0; n < 4; n++)
          atomicAdd(&orow[n0 + wc*64 + n*16 + ccol], (acc[m][n][j2] + bias[n]) * wv);
      }
    }
  }
}

extern "C" void kernel_launch(void* const* d_in, const int* in_sizes, int n_in,
                              void* d_out, int out_size, void* d_ws, size_t ws_size,
                              hipStream_t stream) {
  const float* x  = (const float*)d_in[0];
  const float* Wg = (const float*)d_in[1];
  const float* bg = (const float*)d_in[2];
  const float* W1 = (const float*)d_in[3];
  const float* b1 = (const float*)d_in[4];
  const float* W2 = (const float*)d_in[5];
  const float* b2 = (const float*)d_in[6];
  float* out = (float*)d_out;

  char* ws = (char*)d_ws;
  const size_t MB = 1024 * 1024;
  int*   expert_count  = (int*)(ws + 0);
  int*   nt1           = (int*)(ws + 64);
  int*   nt2           = (int*)(ws + 68);
  int*   expert_offset = (int*)(ws + 128);
  int*   table1        = (int*)(ws + 1024);
  int*   table2        = (int*)(ws + 2048);
  int*   topk_idx      = (int*)(ws + 4096);
  float* topk_w        = (float*)(ws + 4096 + 32768);
  int*   pair_token    = (int*)(ws + 4096 + 65536);
  float* pair_w        = (float*)(ws + 4096 + 98304);
  unsigned short* xb   = (unsigned short*)(ws + 1*MB);    //  8 MiB
  unsigned short* Wt1  = (unsigned short*)(ws + 9*MB);    // 64 MiB

  const bool roomy = ws_size >= 201ull * MB;
  unsigned short* Wt2 = roomy ? (unsigned short*)(ws + 73*MB) : Wt1;
  unsigned short* h   = roomy ? (unsigned short*)(ws + 137*MB)
                              : (unsigned short*)(ws + 73*MB);

  hipMemsetAsync(ws, 0, 256, stream);
  hipMemsetAsync(d_out, 0, (size_t)N_TOK * DIM * sizeof(float), stream);

  // K1: gate + x->bf16 + W1 transpose
  gate_t1_kernel<<<N_TOK/4 + T1J, 256, 0, stream>>>(x, Wg, bg, topk_idx, topk_w,
                                                    expert_count, xb, W1, Wt1);
  // K2: routing
  route_kernel<<<1, 512, 0, stream>>>(expert_count, expert_offset, table1, nt1,
                                      table2, nt2, topk_idx, topk_w,
                                      pair_token, pair_w);
  // K3: ffn1 (+ W2 transpose fused when workspace allows)
  if (roomy) {
    ffn1_t2_kernel<<<G1 + T2J, 512, 0, stream>>>(xb, Wt1, b1, pair_token, table1,
                                                 nt1, h, W2, Wt2, T2J);
  } else {
    ffn1_t2_kernel<<<G1, 512, 0, stream>>>(xb, Wt1, b1, pair_token, table1,
                                           nt1, h, W2, Wt2, 0);
    transpose_kernel<<<dim3(DIM/64, HID/64, NEXP), 256, 0, stream>>>(W2, Wt2, HID, DIM);
  }
  // K4: ffn2 full-K with L2-locality job order + atomic combine
  ffn2_kernel<<<G2, 256, 0, stream>>>(h, Wt2, b2, pair_token, pair_w, table2, nt2, out);
}